// Round 1
// baseline (522.768 us; speedup 1.0000x reference)
//
#include <hip/hip_runtime.h>

// TimeSeriesAttention: B=4, T=4096, D=64, fp32.
//  enc = tanh(softmax(x@W1+b1)@W2+b2)
//  s[j,i] = <x[j],enc[i]> ; P = softmax rows j ; out[i,d] = sum_j P[j,i] x[j,d]
// Two-pass: (A) per-row m[j], Z[j] via online softmax; (B) out += exp(s-m)*rZ * x.

#define TT   4096
#define BB   4
#define BT   (BB*TT)      // 16384 rows
#define SPLIT_A 4
#define SPLIT_B 2

// ---- tile loaders: 64x64 fp32 tile, 256 threads -------------------------
// thread t loads row r=t>>2, cols (t&3)*16 .. +15 (4x float4, coalesced)

__device__ __forceinline__ void load_tile_T(const float* __restrict__ g,
                                            float* __restrict__ ldsT, int tid) {
  int r = tid >> 2, c0 = (tid & 3) << 4;
  const float4* src = (const float4*)(g + (size_t)r * 64 + c0);
  float4 v0 = src[0], v1 = src[1], v2 = src[2], v3 = src[3];
  float tmp[16] = {v0.x,v0.y,v0.z,v0.w, v1.x,v1.y,v1.z,v1.w,
                   v2.x,v2.y,v2.z,v2.w, v3.x,v3.y,v3.z,v3.w};
#pragma unroll
  for (int e = 0; e < 16; ++e) ldsT[(c0 + e) * 64 + r] = tmp[e];
}

__device__ __forceinline__ void load_tile_both(const float* __restrict__ g,
                                               float* __restrict__ ldsT,
                                               float* __restrict__ ldsN, int tid) {
  int r = tid >> 2, c0 = (tid & 3) << 4;
  const float4* src = (const float4*)(g + (size_t)r * 64 + c0);
  float4 v0 = src[0], v1 = src[1], v2 = src[2], v3 = src[3];
  float4* dstN = (float4*)(ldsN + (size_t)r * 64 + c0);
  dstN[0] = v0; dstN[1] = v1; dstN[2] = v2; dstN[3] = v3;
  float tmp[16] = {v0.x,v0.y,v0.z,v0.w, v1.x,v1.y,v1.z,v1.w,
                   v2.x,v2.y,v2.z,v2.w, v3.x,v3.y,v3.z,v3.w};
#pragma unroll
  for (int e = 0; e < 16; ++e) ldsT[(c0 + e) * 64 + r] = tmp[e];
}

// ---- kernel 1: encoded = tanh(softmax(x@W1+b1)@W2+b2) -------------------
// 256 threads = 4 waves; one row per wave (lane = output feature e).
__global__ __launch_bounds__(256) void k_encode(
    const float* __restrict__ x, const float* __restrict__ W1,
    const float* __restrict__ b1, const float* __restrict__ W2,
    const float* __restrict__ b2, float* __restrict__ enc) {
  __shared__ __align__(16) float W1s[64 * 64];
  __shared__ __align__(16) float W2s[64 * 64];
  __shared__ float xs[4][64];
  __shared__ float hs[4][64];
  int tid = threadIdx.x;
  for (int i = tid; i < 1024; i += 256) {
    ((float4*)W1s)[i] = ((const float4*)W1)[i];
    ((float4*)W2s)[i] = ((const float4*)W2)[i];
  }
  __syncthreads();
  int wave = tid >> 6, lane = tid & 63;
  float bias1 = b1[lane], bias2 = b2[lane];
  int base = blockIdx.x * 64;
  for (int it = 0; it < 16; ++it) {
    int row = base + it * 4 + wave;
    xs[wave][lane] = x[(size_t)row * 64 + lane];
    __syncthreads();
    float h = bias1;
#pragma unroll 16
    for (int d = 0; d < 64; ++d) h = fmaf(xs[wave][d], W1s[d * 64 + lane], h);
    // softmax over 64 lanes
    float m = h;
#pragma unroll
    for (int off = 32; off; off >>= 1) m = fmaxf(m, __shfl_xor(m, off));
    float e = __expf(h - m);
    float ssum = e;
#pragma unroll
    for (int off = 32; off; off >>= 1) ssum += __shfl_xor(ssum, off);
    hs[wave][lane] = e / ssum;
    __syncthreads();
    float h2 = bias2;
#pragma unroll 16
    for (int d = 0; d < 64; ++d) h2 = fmaf(hs[wave][d], W2s[d * 64 + lane], h2);
    enc[(size_t)row * 64 + lane] = tanhf(h2);
    __syncthreads();
  }
}

// ---- kernel 2 (pass A): per-row online softmax stats ---------------------
// block: one 64-row j-tile (blockIdx.x over B*T/64), blockIdx.y = i-split.
// thread(ty,tx): rows j=4ty..+3, cols i=4tx..+3 of the 64x64 score tile.
__global__ __launch_bounds__(256) void k_stats(
    const float* __restrict__ x, const float* __restrict__ enc,
    float* __restrict__ mpart, float* __restrict__ lpart) {
  __shared__ __align__(16) float xsT[64 * 64];
  __shared__ __align__(16) float esT[64 * 64];
  int tid = threadIdx.x, ty = tid >> 4, tx = tid & 15;
  int jt = blockIdx.x;
  int b = jt >> 6;
  int jbase = jt << 6;  // flat row base
  load_tile_T(x + (size_t)jbase * 64, xsT, tid);
  float m_run[4], l_run[4];
#pragma unroll
  for (int r = 0; r < 4; ++r) { m_run[r] = -3e38f; l_run[r] = 0.f; }
  int t0 = blockIdx.y * (64 / SPLIT_A);
  for (int itile = t0; itile < t0 + 64 / SPLIT_A; ++itile) {
    __syncthreads();
    load_tile_T(enc + (((size_t)(b << 12)) + (itile << 6)) * 64, esT, tid);
    __syncthreads();
    float s[4][4] = {{0.f,0.f,0.f,0.f},{0.f,0.f,0.f,0.f},
                     {0.f,0.f,0.f,0.f},{0.f,0.f,0.f,0.f}};
#pragma unroll 16
    for (int k = 0; k < 64; ++k) {
      float4 a4 = *(const float4*)(xsT + k * 64 + 4 * ty);
      float4 b4 = *(const float4*)(esT + k * 64 + 4 * tx);
      float av[4] = {a4.x, a4.y, a4.z, a4.w};
      float bv[4] = {b4.x, b4.y, b4.z, b4.w};
#pragma unroll
      for (int r = 0; r < 4; ++r)
#pragma unroll
        for (int c = 0; c < 4; ++c) s[r][c] = fmaf(av[r], bv[c], s[r][c]);
    }
#pragma unroll
    for (int r = 0; r < 4; ++r) {
      float tm = fmaxf(fmaxf(s[r][0], s[r][1]), fmaxf(s[r][2], s[r][3]));
      tm = fmaxf(tm, __shfl_xor(tm, 1));
      tm = fmaxf(tm, __shfl_xor(tm, 2));
      tm = fmaxf(tm, __shfl_xor(tm, 4));
      tm = fmaxf(tm, __shfl_xor(tm, 8));
      float nm = fmaxf(m_run[r], tm);
      float ps = __expf(s[r][0] - nm) + __expf(s[r][1] - nm) +
                 __expf(s[r][2] - nm) + __expf(s[r][3] - nm);
      ps += __shfl_xor(ps, 1);
      ps += __shfl_xor(ps, 2);
      ps += __shfl_xor(ps, 4);
      ps += __shfl_xor(ps, 8);
      l_run[r] = l_run[r] * __expf(m_run[r] - nm) + ps;
      m_run[r] = nm;
    }
  }
  if (tx == 0) {
#pragma unroll
    for (int r = 0; r < 4; ++r) {
      int row = jbase + 4 * ty + r;
      mpart[(size_t)blockIdx.y * BT + row] = m_run[r];
      lpart[(size_t)blockIdx.y * BT + row] = l_run[r];
    }
  }
}

// ---- kernel 3: merge split stats → m, 1/Z --------------------------------
__global__ __launch_bounds__(256) void k_merge(
    const float* __restrict__ mpart, const float* __restrict__ lpart,
    float* __restrict__ mrow, float* __restrict__ rZ) {
  int j = blockIdx.x * 256 + threadIdx.x;
  float m = -3e38f;
#pragma unroll
  for (int s2 = 0; s2 < SPLIT_A; ++s2) m = fmaxf(m, mpart[(size_t)s2 * BT + j]);
  float Z = 0.f;
#pragma unroll
  for (int s2 = 0; s2 < SPLIT_A; ++s2)
    Z += lpart[(size_t)s2 * BT + j] * __expf(mpart[(size_t)s2 * BT + j] - m);
  mrow[j] = m;
  rZ[j] = 1.0f / Z;
}

// ---- kernel 4 (pass B): out[i,d] += sum_j exp(s[j,i]-m[j])*rZ[j]*x[j,d] --
// block owns a 64-row i-tile; loops j-tiles of its split.
// score tile computed transposed: sT[i][j], rows i=4ty, cols j=4tx.
// xsTW holds x^T for the score matmul, then is reused for W[j][i].
__global__ __launch_bounds__(256) void k_out(
    const float* __restrict__ x, const float* __restrict__ enc,
    const float* __restrict__ mrow, const float* __restrict__ rZ,
    float* __restrict__ out) {
  __shared__ __align__(16) float esT[64 * 64];
  __shared__ __align__(16) float xsTW[64 * 64];
  __shared__ __align__(16) float xsN[64 * 64];
  int tid = threadIdx.x, ty = tid >> 4, tx = tid & 15;
  int it = blockIdx.x;
  int b = it >> 6;
  int ibase = it << 6;  // flat row base for enc/out
  load_tile_T(enc + (size_t)ibase * 64, esT, tid);
  float o[4][4] = {{0.f,0.f,0.f,0.f},{0.f,0.f,0.f,0.f},
                   {0.f,0.f,0.f,0.f},{0.f,0.f,0.f,0.f}};
  int t0 = blockIdx.y * (64 / SPLIT_B);
  for (int jtile = t0; jtile < t0 + 64 / SPLIT_B; ++jtile) {
    int jbase = (b << 12) + (jtile << 6);
    float mj[4], zj[4];
#pragma unroll
    for (int c = 0; c < 4; ++c) {
      mj[c] = mrow[jbase + 4 * tx + c];
      zj[c] = rZ[jbase + 4 * tx + c];
    }
    __syncthreads();  // WAR: previous iter done with xsTW/xsN
    load_tile_both(x + (size_t)jbase * 64, xsTW, xsN, tid);
    __syncthreads();  // tiles ready
    float s[4][4] = {{0.f,0.f,0.f,0.f},{0.f,0.f,0.f,0.f},
                     {0.f,0.f,0.f,0.f},{0.f,0.f,0.f,0.f}};
#pragma unroll 16
    for (int k = 0; k < 64; ++k) {
      float4 a4 = *(const float4*)(esT + k * 64 + 4 * ty);
      float4 b4 = *(const float4*)(xsTW + k * 64 + 4 * tx);
      float av[4] = {a4.x, a4.y, a4.z, a4.w};
      float bv[4] = {b4.x, b4.y, b4.z, b4.w};
#pragma unroll
      for (int r = 0; r < 4; ++r)
#pragma unroll
        for (int c = 0; c < 4; ++c) s[r][c] = fmaf(av[r], bv[c], s[r][c]);
    }
    // weights in-place: s[r][c] = exp(sT - m[j]) * rZ[j], j = jbase+4tx+c
#pragma unroll
    for (int c = 0; c < 4; ++c)
#pragma unroll
      for (int r = 0; r < 4; ++r) s[r][c] = __expf(s[r][c] - mj[c]) * zj[c];
    __syncthreads();  // all reads of xsTW (x^T) done
    // store W[j][i]: row j contiguous in i
#pragma unroll
    for (int c = 0; c < 4; ++c)
      *(float4*)(xsTW + (4 * tx + c) * 64 + 4 * ty) =
          make_float4(s[0][c], s[1][c], s[2][c], s[3][c]);
    __syncthreads();  // W ready
#pragma unroll 16
    for (int k = 0; k < 64; ++k) {
      float4 a4 = *(const float4*)(xsTW + k * 64 + 4 * ty);  // W[j=k][i]
      float4 b4 = *(const float4*)(xsN + k * 64 + 4 * tx);   // x[j=k][d]
      float av[4] = {a4.x, a4.y, a4.z, a4.w};
      float bv[4] = {b4.x, b4.y, b4.z, b4.w};
#pragma unroll
      for (int r = 0; r < 4; ++r)
#pragma unroll
        for (int c = 0; c < 4; ++c) o[r][c] = fmaf(av[r], bv[c], o[r][c]);
    }
  }
#pragma unroll
  for (int r = 0; r < 4; ++r)
#pragma unroll
    for (int c = 0; c < 4; ++c)
      atomicAdd(out + (size_t)(ibase + 4 * ty + r) * 64 + 4 * tx + c, o[r][c]);
}

extern "C" void kernel_launch(void* const* d_in, const int* in_sizes, int n_in,
                              void* d_out, int out_size, void* d_ws,
                              size_t ws_size, hipStream_t stream) {
  const float* x  = (const float*)d_in[0];
  const float* W1 = (const float*)d_in[1];
  const float* b1 = (const float*)d_in[2];
  const float* W2 = (const float*)d_in[3];
  const float* b2 = (const float*)d_in[4];
  float* out = (float*)d_out;

  float* enc   = (float*)d_ws;                 // BT*64 floats (4 MB)
  float* mrow  = enc + (size_t)BT * 64;        // BT
  float* rZv   = mrow + BT;                    // BT
  float* mpart = rZv + BT;                     // SPLIT_A*BT
  float* lpart = mpart + (size_t)SPLIT_A * BT; // SPLIT_A*BT

  hipMemsetAsync(d_out, 0, (size_t)out_size * sizeof(float), stream);
  k_encode<<<dim3(BT / 64), dim3(256), 0, stream>>>(x, W1, b1, W2, b2, enc);
  k_stats<<<dim3(BT / 64, SPLIT_A), dim3(256), 0, stream>>>(x, enc, mpart, lpart);
  k_merge<<<dim3(BT / 256), dim3(256), 0, stream>>>(mpart, lpart, mrow, rZv);
  k_out<<<dim3(BT / 64, SPLIT_B), dim3(256), 0, stream>>>(x, enc, mrow, rZv, out);
}

// Round 2
// 284.213 us; speedup vs baseline: 1.8394x; 1.8394x over previous
//
#include <hip/hip_runtime.h>

// TimeSeriesAttention B=4,T=4096,D=64 fp32 — MFMA f16-split version.
//  enc = tanh(softmax(x@W1+b1)@W2+b2)
//  s[j,i]=<x_j,enc_i>; P = softmax over i per row j; out[i,d] = sum_j P[j,i] x[j,d]
// All big matmuls: 2-term f16 split (hi+lo), 3 MFMA products per MAC-set.
// mfma_f32_16x16x32_f16: A[m=lane&15][k=quad*8+t], B^T[n=lane&15][k=quad*8+t],
// C/D: col=lane&15 (n), row=quad*4+reg (m).

typedef _Float16 f16;
typedef __attribute__((ext_vector_type(8))) _Float16 f16x8;
typedef __attribute__((ext_vector_type(4))) _Float16 f16x4;
typedef __attribute__((ext_vector_type(4))) float f32x4;

#define TT 4096
#define BB 4
#define BT (BB*TT)
#define SPLIT_A 8
#define SPLIT_B 4

#define MFMA16(A,B,C) __builtin_amdgcn_mfma_f32_16x16x32_f16(A,B,C,0,0,0)

// ---- prep: x fp32 -> x_hi/x_lo [BT][64] and xT_hi/xT_lo [B][64][T] ------
__global__ __launch_bounds__(256) void k_prep(const float* __restrict__ x,
    f16* __restrict__ xh, f16* __restrict__ xl,
    f16* __restrict__ xth, f16* __restrict__ xtl) {
  __shared__ float tile[64][65];
  int tid = threadIdx.x;
  int r = tid >> 2, c0 = (tid & 3) << 4;
  int jbase = blockIdx.x * 64;
  int b = jbase >> 12, tloc = jbase & (TT - 1);
  const float4* src = (const float4*)(x + (size_t)(jbase + r) * 64 + c0);
  float v[16];
  {
    float4 a0 = src[0], a1 = src[1], a2 = src[2], a3 = src[3];
    v[0]=a0.x; v[1]=a0.y; v[2]=a0.z; v[3]=a0.w;
    v[4]=a1.x; v[5]=a1.y; v[6]=a1.z; v[7]=a1.w;
    v[8]=a2.x; v[9]=a2.y; v[10]=a2.z; v[11]=a2.w;
    v[12]=a3.x; v[13]=a3.y; v[14]=a3.z; v[15]=a3.w;
  }
  f16 hbuf[16], lbuf[16];
#pragma unroll
  for (int e = 0; e < 16; ++e) {
    tile[r][c0 + e] = v[e];
    f16 h = (f16)v[e];
    hbuf[e] = h; lbuf[e] = (f16)(v[e] - (float)h);
  }
  size_t rowoff = (size_t)(jbase + r) * 64 + c0;
  *(f16x8*)(xh + rowoff) = *(f16x8*)&hbuf[0];
  *(f16x8*)(xh + rowoff + 8) = *(f16x8*)&hbuf[8];
  *(f16x8*)(xl + rowoff) = *(f16x8*)&lbuf[0];
  *(f16x8*)(xl + rowoff + 8) = *(f16x8*)&lbuf[8];
  __syncthreads();
  // transpose: thread writes d-row r, t-cols tloc+c0..+15
#pragma unroll
  for (int e = 0; e < 16; ++e) {
    float val = tile[c0 + e][r];
    f16 h = (f16)val;
    hbuf[e] = h; lbuf[e] = (f16)(val - (float)h);
  }
  size_t toff = ((size_t)(b * 64 + r)) * TT + tloc + c0;
  *(f16x8*)(xth + toff) = *(f16x8*)&hbuf[0];
  *(f16x8*)(xth + toff + 8) = *(f16x8*)&hbuf[8];
  *(f16x8*)(xtl + toff) = *(f16x8*)&lbuf[0];
  *(f16x8*)(xtl + toff + 8) = *(f16x8*)&lbuf[8];
}

// ---- encode: per-row MLP, outputs enc_hi/enc_lo f16 ----------------------
__global__ __launch_bounds__(256) void k_encode(
    const float* __restrict__ x, const float* __restrict__ W1,
    const float* __restrict__ b1, const float* __restrict__ W2,
    const float* __restrict__ b2, f16* __restrict__ eh, f16* __restrict__ el) {
  __shared__ __align__(16) float W1s[64 * 64];
  __shared__ __align__(16) float W2s[64 * 64];
  __shared__ float xs[4][64];
  __shared__ float hs[4][64];
  int tid = threadIdx.x;
  for (int i = tid; i < 1024; i += 256) {
    ((float4*)W1s)[i] = ((const float4*)W1)[i];
    ((float4*)W2s)[i] = ((const float4*)W2)[i];
  }
  __syncthreads();
  int wave = tid >> 6, lane = tid & 63;
  float bias1 = b1[lane], bias2 = b2[lane];
  int base = blockIdx.x * 64;
  for (int it = 0; it < 16; ++it) {
    int row = base + it * 4 + wave;
    xs[wave][lane] = x[(size_t)row * 64 + lane];
    __syncthreads();
    float h = bias1;
#pragma unroll 16
    for (int d = 0; d < 64; ++d) h = fmaf(xs[wave][d], W1s[d * 64 + lane], h);
    float m = h;
#pragma unroll
    for (int off = 32; off; off >>= 1) m = fmaxf(m, __shfl_xor(m, off));
    float e = __expf(h - m);
    float ssum = e;
#pragma unroll
    for (int off = 32; off; off >>= 1) ssum += __shfl_xor(ssum, off);
    hs[wave][lane] = e / ssum;
    __syncthreads();
    float h2 = bias2;
#pragma unroll 16
    for (int d = 0; d < 64; ++d) h2 = fmaf(hs[wave][d], W2s[d * 64 + lane], h2);
    float val = tanhf(h2);
    f16 vh = (f16)val;
    eh[(size_t)row * 64 + lane] = vh;
    el[(size_t)row * 64 + lane] = (f16)(val - (float)vh);
    __syncthreads();
  }
}

// ---- pass A: online-softmax row stats via MFMA, no LDS -------------------
// block: 4 waves, wave owns 64 j-rows (resident x A-frags); streams enc.
__global__ __launch_bounds__(256, 2) void k_statsM(
    const f16* __restrict__ xh, const f16* __restrict__ xl,
    const f16* __restrict__ eh, const f16* __restrict__ el,
    float* __restrict__ mpart, float* __restrict__ lpart) {
  int tid = threadIdx.x;
  int w = tid >> 6, lane = tid & 63, quad = lane >> 4, l15 = lane & 15;
  int jb = blockIdx.x * 256 + w * 64;
  int b = (blockIdx.x * 256) >> 12;
  f16x8 xa[4][2][2];
#pragma unroll
  for (int mt = 0; mt < 4; ++mt)
#pragma unroll
    for (int kc = 0; kc < 2; ++kc) {
      size_t off = ((size_t)(jb + mt * 16 + l15)) * 64 + kc * 32 + quad * 8;
      xa[mt][kc][0] = *(const f16x8*)(xh + off);
      xa[mt][kc][1] = *(const f16x8*)(xl + off);
    }
  float m_run[16], l_run[16];
#pragma unroll
  for (int s = 0; s < 16; ++s) { m_run[s] = -3e38f; l_run[s] = 0.f; }

  int i0 = blockIdx.y * (TT / SPLIT_A);
  for (int it = 0; it < TT / SPLIT_A / 64; ++it) {
    int ibase = b * TT + i0 + it * 64;
    f16x8 ebf[4][2][2];
#pragma unroll
    for (int nt = 0; nt < 4; ++nt)
#pragma unroll
      for (int kc = 0; kc < 2; ++kc) {
        size_t off = ((size_t)(ibase + nt * 16 + l15)) * 64 + kc * 32 + quad * 8;
        ebf[nt][kc][0] = *(const f16x8*)(eh + off);
        ebf[nt][kc][1] = *(const f16x8*)(el + off);
      }
    f32x4 acc[4][4];
#pragma unroll
    for (int mt = 0; mt < 4; ++mt)
#pragma unroll
      for (int nt = 0; nt < 4; ++nt) {
        f32x4 z = {0.f, 0.f, 0.f, 0.f};
        acc[mt][nt] = z;
      }
#pragma unroll
    for (int kc = 0; kc < 2; ++kc)
#pragma unroll
      for (int mt = 0; mt < 4; ++mt)
#pragma unroll
        for (int nt = 0; nt < 4; ++nt) {
          acc[mt][nt] = MFMA16(xa[mt][kc][0], ebf[nt][kc][0], acc[mt][nt]);
          acc[mt][nt] = MFMA16(xa[mt][kc][0], ebf[nt][kc][1], acc[mt][nt]);
          acc[mt][nt] = MFMA16(xa[mt][kc][1], ebf[nt][kc][0], acc[mt][nt]);
        }
#pragma unroll
    for (int mt = 0; mt < 4; ++mt)
#pragma unroll
      for (int r = 0; r < 4; ++r) {
        int s = mt * 4 + r;
        float tm = fmaxf(fmaxf(acc[mt][0][r], acc[mt][1][r]),
                         fmaxf(acc[mt][2][r], acc[mt][3][r]));
        tm = fmaxf(tm, __shfl_xor(tm, 1));
        tm = fmaxf(tm, __shfl_xor(tm, 2));
        tm = fmaxf(tm, __shfl_xor(tm, 4));
        tm = fmaxf(tm, __shfl_xor(tm, 8));
        float nm = fmaxf(m_run[s], tm);
        float ps = __expf(acc[mt][0][r] - nm) + __expf(acc[mt][1][r] - nm) +
                   __expf(acc[mt][2][r] - nm) + __expf(acc[mt][3][r] - nm);
        ps += __shfl_xor(ps, 1);
        ps += __shfl_xor(ps, 2);
        ps += __shfl_xor(ps, 4);
        ps += __shfl_xor(ps, 8);
        l_run[s] = l_run[s] * __expf(m_run[s] - nm) + ps;
        m_run[s] = nm;
      }
  }
  if (l15 == 0) {
#pragma unroll
    for (int mt = 0; mt < 4; ++mt)
#pragma unroll
      for (int r = 0; r < 4; ++r) {
        int row = jb + mt * 16 + quad * 4 + r;
        mpart[(size_t)blockIdx.y * BT + row] = m_run[mt * 4 + r];
        lpart[(size_t)blockIdx.y * BT + row] = l_run[mt * 4 + r];
      }
  }
}

// ---- merge split stats ---------------------------------------------------
__global__ __launch_bounds__(256) void k_merge(
    const float* __restrict__ mpart, const float* __restrict__ lpart,
    float* __restrict__ mrow, float* __restrict__ rZ) {
  int j = blockIdx.x * 256 + threadIdx.x;
  float m = -3e38f;
#pragma unroll
  for (int s = 0; s < SPLIT_A; ++s) m = fmaxf(m, mpart[(size_t)s * BT + j]);
  float Z = 0.f;
#pragma unroll
  for (int s = 0; s < SPLIT_A; ++s)
    Z += lpart[(size_t)s * BT + j] * __expf(mpart[(size_t)s * BT + j] - m);
  mrow[j] = m;
  rZ[j] = 1.0f / Z;
}

// ---- pass B: sT = x·enc^T -> P -> outT = xT·P (MFMA) ---------------------
// block: 64 i-rows (enc resident). wave w: sT j-rows 16w (A = x, distinct),
// P via padded LDS, PV: wave w computes outT d-rows 16w (A = xT, distinct),
// P as B-operand read j-contiguously from LDS.
__global__ __launch_bounds__(256, 2) void k_outM(
    const f16* __restrict__ xh, const f16* __restrict__ xl,
    const f16* __restrict__ xth, const f16* __restrict__ xtl,
    const f16* __restrict__ eh, const f16* __restrict__ el,
    const float* __restrict__ mrow, const float* __restrict__ rZ,
    float* __restrict__ out) {
  __shared__ f16 Ph[64][72];
  __shared__ f16 Pl[64][72];
  int tid = threadIdx.x;
  int w = tid >> 6, lane = tid & 63, quad = lane >> 4, l15 = lane & 15;
  int ibase = blockIdx.x * 64;
  int b = ibase >> 12;
  f16x8 ebr[4][2][2];
#pragma unroll
  for (int nt = 0; nt < 4; ++nt)
#pragma unroll
    for (int kc = 0; kc < 2; ++kc) {
      size_t off = ((size_t)(ibase + nt * 16 + l15)) * 64 + kc * 32 + quad * 8;
      ebr[nt][kc][0] = *(const f16x8*)(eh + off);
      ebr[nt][kc][1] = *(const f16x8*)(el + off);
    }
  f32x4 oacc[4];
#pragma unroll
  for (int nt = 0; nt < 4; ++nt) {
    f32x4 z = {0.f, 0.f, 0.f, 0.f};
    oacc[nt] = z;
  }
  int jt0 = blockIdx.y * (TT / SPLIT_B / 64);
  for (int jt = 0; jt < TT / SPLIT_B / 64; ++jt) {
    int jloc = (jt0 + jt) * 64;
    int jb = b * TT + jloc;
    // sT[j,i] for wave's 16 j
    f16x8 xa[2][2];
#pragma unroll
    for (int kc = 0; kc < 2; ++kc) {
      size_t off = ((size_t)(jb + w * 16 + l15)) * 64 + kc * 32 + quad * 8;
      xa[kc][0] = *(const f16x8*)(xh + off);
      xa[kc][1] = *(const f16x8*)(xl + off);
    }
    f32x4 sacc[4];
#pragma unroll
    for (int nt = 0; nt < 4; ++nt) {
      f32x4 z = {0.f, 0.f, 0.f, 0.f};
      sacc[nt] = z;
    }
#pragma unroll
    for (int kc = 0; kc < 2; ++kc)
#pragma unroll
      for (int nt = 0; nt < 4; ++nt) {
        sacc[nt] = MFMA16(xa[kc][0], ebr[nt][kc][0], sacc[nt]);
        sacc[nt] = MFMA16(xa[kc][0], ebr[nt][kc][1], sacc[nt]);
        sacc[nt] = MFMA16(xa[kc][1], ebr[nt][kc][0], sacc[nt]);
      }
    float mj[4], zj[4];
#pragma unroll
    for (int r = 0; r < 4; ++r) {
      int j = jb + w * 16 + quad * 4 + r;
      mj[r] = mrow[j];
      zj[r] = rZ[j];
    }
#pragma unroll
    for (int nt = 0; nt < 4; ++nt) {
      f16x4 vh, vl;
#pragma unroll
      for (int r = 0; r < 4; ++r) {
        float p = __expf(sacc[nt][r] - mj[r]) * zj[r];
        f16 ph = (f16)p;
        vh[r] = ph;
        vl[r] = (f16)(p - (float)ph);
      }
      int i = nt * 16 + l15;
      *(f16x4*)&Ph[i][w * 16 + quad * 4] = vh;
      *(f16x4*)&Pl[i][w * 16 + quad * 4] = vl;
    }
    __syncthreads();  // P ready for all waves
    // outT[d,i] += sum_j xT[d,j] * P[j,i]; wave w: d-rows 16w..+15
#pragma unroll
    for (int kc = 0; kc < 2; ++kc) {
      size_t off = ((size_t)(b * 64 + w * 16 + l15)) * TT + jloc + kc * 32 + quad * 8;
      f16x8 ta_h = *(const f16x8*)(xth + off);
      f16x8 ta_l = *(const f16x8*)(xtl + off);
#pragma unroll
      for (int nt = 0; nt < 4; ++nt) {
        f16x8 pb_h = *(const f16x8*)&Ph[nt * 16 + l15][kc * 32 + quad * 8];
        f16x8 pb_l = *(const f16x8*)&Pl[nt * 16 + l15][kc * 32 + quad * 8];
        oacc[nt] = MFMA16(ta_h, pb_h, oacc[nt]);
        oacc[nt] = MFMA16(ta_h, pb_l, oacc[nt]);
        oacc[nt] = MFMA16(ta_l, pb_h, oacc[nt]);
      }
    }
    __syncthreads();  // PV reads done before next iter's P writes
  }
  // D[m=d][n=i]: col=i (l15), row=d (quad*4+reg), wave offset 16w on d
#pragma unroll
  for (int nt = 0; nt < 4; ++nt) {
    int i = ibase + nt * 16 + l15;
#pragma unroll
    for (int r = 0; r < 4; ++r) {
      int d = w * 16 + quad * 4 + r;
      atomicAdd(out + (size_t)i * 64 + d, oacc[nt][r]);
    }
  }
}

extern "C" void kernel_launch(void* const* d_in, const int* in_sizes, int n_in,
                              void* d_out, int out_size, void* d_ws,
                              size_t ws_size, hipStream_t stream) {
  const float* x = (const float*)d_in[0];
  const float* W1 = (const float*)d_in[1];
  const float* b1 = (const float*)d_in[2];
  const float* W2 = (const float*)d_in[3];
  const float* b2 = (const float*)d_in[4];
  float* out = (float*)d_out;

  f16* xh = (f16*)d_ws;                       // BT*64 each
  f16* xl = xh + (size_t)BT * 64;
  f16* xth = xl + (size_t)BT * 64;
  f16* xtl = xth + (size_t)BT * 64;
  f16* eh = xtl + (size_t)BT * 64;
  f16* el = eh + (size_t)BT * 64;
  float* mrow = (float*)(el + (size_t)BT * 64);
  float* rZv = mrow + BT;
  float* mpart = rZv + BT;
  float* lpart = mpart + (size_t)SPLIT_A * BT;

  hipMemsetAsync(d_out, 0, (size_t)out_size * sizeof(float), stream);
  k_prep<<<dim3(BT / 64), dim3(256), 0, stream>>>(x, xh, xl, xth, xtl);
  k_encode<<<dim3(BT / 64), dim3(256), 0, stream>>>(x, W1, b1, W2, b2, eh, el);
  k_statsM<<<dim3(BT / 256, SPLIT_A), dim3(256), 0, stream>>>(xh, xl, eh, el,
                                                              mpart, lpart);
  k_merge<<<dim3(BT / 256), dim3(256), 0, stream>>>(mpart, lpart, mrow, rZv);
  k_outM<<<dim3(BT / 64, SPLIT_B), dim3(256), 0, stream>>>(
      xh, xl, xth, xtl, eh, el, mrow, rZv, out);
}